// Round 8
// baseline (298.536 us; speedup 1.0000x reference)
//
#include <hip/hip_runtime.h>
#include <cstddef>
#include <cstdint>

#define L_SEQ 1024
#define NCHUNK 64
#define CLEN 16

typedef __bf16 bf16x8 __attribute__((ext_vector_type(8)));
typedef float f32x4 __attribute__((ext_vector_type(4)));

__device__ __forceinline__ float silu_f(float x) {
    return x / (1.f + __expf(-x));
}
__device__ __forceinline__ float exp2_fast(float x) { return exp2f(x); }

__device__ __forceinline__ unsigned short f2bf(float x) {
    union { float f; unsigned int u; } v; v.f = x;
    unsigned int r = (v.u + 0x7fffu + ((v.u >> 16) & 1u)) >> 16;
    return (unsigned short)r;
}
__device__ __forceinline__ float bf2f(unsigned short h) {
    union { float f; unsigned int u; } v; v.u = ((unsigned int)h) << 16;
    return v.f;
}
__device__ __forceinline__ unsigned int packf(float x) {
    unsigned short h = f2bf(x);
    unsigned short l = f2bf(x - bf2f(h));
    return ((unsigned int)h << 16) | (unsigned int)l;
}
__device__ __forceinline__ float unpackf(unsigned int pk) {
    return bf2f((unsigned short)(pk >> 16)) + bf2f((unsigned short)(pk & 0xffffu));
}
__device__ __forceinline__ bf16x8 u4_to_bf8(uint4 u) {
    return __builtin_bit_cast(bf16x8, u);
}

// ---------------- bf16x3 MFMA GEMM: LDS-FREE, barrier-free frag-direct loads ----------
// Each of 4 waves owns a 64x64 quadrant of the 128x128 block tile and loads its MFMA
// fragments straight from L2 (A row-major [M][K], B transposed [N][K] — fragment
// layout == contiguous 16B row slices). No LDS, no __syncthreads in the K-loop.
// Split-K via blockIdx.z (SPLITS). XCD swizzle (m-contiguous per XCD) when grid %8==0.
// EPI 1: bf16 hi/lo planes (ldc=Nw). EPI 3: raw f32 partial (cols<Nw) to split-partial
// buffer selected from Cf/Cf2. EPI 4: +bias; cols<768 -> Cf, else Cf2.
template<bool APK, int EPI, int SPLITS>
__global__ __launch_bounds__(256)
void gemm_bf3(const unsigned short* __restrict__ Ahi,
              const unsigned short* __restrict__ Alo,
              const unsigned int* __restrict__ Apk, int lda,
              const unsigned short* __restrict__ Bthi,
              const unsigned short* __restrict__ Btlo,
              const float* __restrict__ bias,
              float* __restrict__ Cf, float* __restrict__ Cf2,
              unsigned short* __restrict__ Chi, unsigned short* __restrict__ Clo,
              int Ks, int Ktot, int Nw)
{
    const int tid = threadIdx.x;
    const int lane = tid & 63;
    const int wave = tid >> 6;
    const int wm = wave >> 1, wn = wave & 1;

    const int gx = gridDim.x;
    const int nwg = gx * gridDim.y;
    const int lin = blockIdx.y * gx + blockIdx.x;
    const int swz = ((nwg & 7) == 0) ? ((lin & 7) * (nwg >> 3) + (lin >> 3)) : lin;
    const int m0 = (swz / gx) * 128, n0 = (swz % gx) * 128;
    const int z = (SPLITS > 1) ? blockIdx.z : 0;
    const int kbeg = z * Ks;
    const int kend = kbeg + Ks;

    const int fr = lane & 15;
    const int kq8 = (lane >> 4) * 8;
    const int mbw = m0 + wm * 64, nbw = n0 + wn * 64;

    unsigned int aoffs[4], boffs[4];
    #pragma unroll
    for (int i = 0; i < 4; ++i)
        aoffs[i] = (unsigned int)(mbw + i * 16 + fr) * (unsigned int)lda + kq8;
    #pragma unroll
    for (int j = 0; j < 4; ++j)
        boffs[j] = (unsigned int)(nbw + j * 16 + fr) * (unsigned int)Ktot + kq8;

    f32x4 acc[4][4];
    #pragma unroll
    for (int i = 0; i < 4; ++i)
        #pragma unroll
        for (int j = 0; j < 4; ++j) {
            f32x4 zz = {0.f, 0.f, 0.f, 0.f};
            acc[i][j] = zz;
        }

    for (int k0 = kbeg; k0 < kend; k0 += 32) {
        bf16x8 aH[4], aL[4];
        if constexpr (APK) {
            #pragma unroll
            for (int i = 0; i < 4; ++i) {
                const unsigned int* p = Apk + aoffs[i] + k0;
                uint4 p0 = *(const uint4*)p;
                uint4 p1 = *(const uint4*)(p + 4);
                uint4 h, l;
                h.x = (p0.x >> 16) | (p0.y & 0xffff0000u);
                h.y = (p0.z >> 16) | (p0.w & 0xffff0000u);
                h.z = (p1.x >> 16) | (p1.y & 0xffff0000u);
                h.w = (p1.z >> 16) | (p1.w & 0xffff0000u);
                l.x = (p0.x & 0xffffu) | (p0.y << 16);
                l.y = (p0.z & 0xffffu) | (p0.w << 16);
                l.z = (p1.x & 0xffffu) | (p1.y << 16);
                l.w = (p1.z & 0xffffu) | (p1.w << 16);
                aH[i] = u4_to_bf8(h);
                aL[i] = u4_to_bf8(l);
            }
        } else {
            #pragma unroll
            for (int i = 0; i < 4; ++i) {
                aH[i] = *(const bf16x8*)(Ahi + aoffs[i] + k0);
                aL[i] = *(const bf16x8*)(Alo + aoffs[i] + k0);
            }
        }
        #pragma unroll
        for (int j = 0; j < 4; ++j) {
            bf16x8 bH = *(const bf16x8*)(Bthi + boffs[j] + k0);
            bf16x8 bL = *(const bf16x8*)(Btlo + boffs[j] + k0);
            #pragma unroll
            for (int i = 0; i < 4; ++i)
                acc[i][j] = __builtin_amdgcn_mfma_f32_16x16x32_bf16(aH[i], bH, acc[i][j], 0, 0, 0);
            #pragma unroll
            for (int i = 0; i < 4; ++i)
                acc[i][j] = __builtin_amdgcn_mfma_f32_16x16x32_bf16(aL[i], bH, acc[i][j], 0, 0, 0);
            #pragma unroll
            for (int i = 0; i < 4; ++i)
                acc[i][j] = __builtin_amdgcn_mfma_f32_16x16x32_bf16(aH[i], bL, acc[i][j], 0, 0, 0);
        }
    }

    // epilogue
    float* myP = nullptr;
    if constexpr (EPI == 3) {
        float* base = (2 * z >= SPLITS) ? Cf2 : Cf;
        int sub = z - ((2 * z >= SPLITS) ? SPLITS / 2 : 0);
        myP = base + (size_t)sub * (size_t)(gridDim.y * 128) * Nw;
    }
    const int col = lane & 15, rq = lane >> 4;
    #pragma unroll
    for (int j = 0; j < 4; ++j) {
        int nn = n0 + wn * 64 + j * 16 + col;
        float bv = 0.f;
        if constexpr (EPI == 1 || EPI == 4) { if (bias) bv = bias[nn]; }
        #pragma unroll
        for (int i = 0; i < 4; ++i) {
            int mb = m0 + wm * 64 + i * 16 + rq * 4;
            #pragma unroll
            for (int r = 0; r < 4; ++r) {
                float o = acc[i][j][r] + bv;
                if constexpr (EPI == 1) {
                    unsigned short h = f2bf(o);
                    Chi[(size_t)(mb + r) * Nw + nn] = h;
                    Clo[(size_t)(mb + r) * Nw + nn] = f2bf(o - bf2f(h));
                } else if constexpr (EPI == 3) {
                    if (nn < Nw) myP[(size_t)(mb + r) * Nw + nn] = o;
                } else if constexpr (EPI == 4) {
                    if (nn < 768) Cf[(size_t)(mb + r) * 768 + nn] = o;
                    else          Cf2[(size_t)(mb + r) * 768 + (nn - 768)] = o;
                }
            }
        }
    }
}

// ---------------- fused one-shot prep ----------------
__device__ __forceinline__ void wcvt_body(const float* __restrict__ W,
                                          unsigned short* __restrict__ Thi,
                                          unsigned short* __restrict__ Tlo,
                                          int K, int N, int nx, int local, int tid,
                                          float* t /* [32][33] */)
{
    const int n0 = (local % nx) * 32, k0 = (local / nx) * 32;
    const int r = tid >> 3, c4 = (tid & 7) * 4;
    float4 v = *(const float4*)(W + (size_t)(k0 + r) * N + n0 + c4);
    t[r * 33 + c4 + 0] = v.x; t[r * 33 + c4 + 1] = v.y;
    t[r * 33 + c4 + 2] = v.z; t[r * 33 + c4 + 3] = v.w;
    __syncthreads();
    unsigned short hs[4], ls[4];
    #pragma unroll
    for (int j = 0; j < 4; ++j) {
        float x = t[(c4 + j) * 33 + r];
        hs[j] = f2bf(x);
        ls[j] = f2bf(x - bf2f(hs[j]));
    }
    size_t o = (size_t)(n0 + r) * K + k0 + c4;
    uint2 hv, lv;
    hv.x = (unsigned)hs[0] | ((unsigned)hs[1] << 16);
    hv.y = (unsigned)hs[2] | ((unsigned)hs[3] << 16);
    lv.x = (unsigned)ls[0] | ((unsigned)ls[1] << 16);
    lv.y = (unsigned)ls[2] | ((unsigned)ls[3] << 16);
    *(uint2*)(Thi + o) = hv;
    *(uint2*)(Tlo + o) = lv;
}

__global__ __launch_bounds__(256)
void prep_all(const float* __restrict__ W_proj, const float* __restrict__ W_in,
              const float* __restrict__ W_out, const float* __restrict__ W_x,
              const float* __restrict__ W_dt, const float* __restrict__ b_proj,
              const float* __restrict__ W_ev, const float* __restrict__ W_rgb,
              const float* __restrict__ b_ev, const float* __restrict__ b_rgb,
              const float* __restrict__ ev, const float* __restrict__ rgb,
              unsigned short* __restrict__ wtp_hi, unsigned short* __restrict__ wtp_lo,
              unsigned short* __restrict__ wti_hi, unsigned short* __restrict__ wti_lo,
              unsigned short* __restrict__ wto_hi, unsigned short* __restrict__ wto_lo,
              unsigned short* __restrict__ btc_hi, unsigned short* __restrict__ btc_lo,
              unsigned short* __restrict__ wct_hi, unsigned short* __restrict__ wct_lo,
              unsigned short* __restrict__ wpd_hi, unsigned short* __restrict__ wpd_lo,
              float* __restrict__ biascat, float* __restrict__ bias_pi,
              unsigned int* __restrict__ apk)
{
    __shared__ float t[32 * 33];
    const int blk = blockIdx.x;
    const int tid = threadIdx.x;
    if (blk < 144) {
        wcvt_body(W_proj, wtp_hi, wtp_lo, 384, 384, 12, blk, tid, t);
    } else if (blk < 720) {
        wcvt_body(W_in, wti_hi, wti_lo, 384, 1536, 48, blk - 144, tid, t);
    } else if (blk < 1008) {
        wcvt_body(W_out, wto_hi, wto_lo, 768, 384, 12, blk - 720, tid, t);
    } else if (blk < 1392) {
        const int flat = (blk - 1008) * 256 + tid;      // 128*768
        const int r = flat / 768, k = flat % 768;
        const int row = (r < 32) ? r : (768 + r);       // 0..31 or 800..895
        float val = (r < 32) ? W_x[(size_t)k * 56 + 24 + r] : 0.f;
        unsigned short h = f2bf(val);
        btc_hi[(size_t)row * 768 + k] = h;
        btc_lo[(size_t)row * 768 + k] = f2bf(val - bf2f(h));
    } else if (blk < 3696) {
        const int flat = (blk - 1392) * 256 + tid;      // 768*768
        const int j = flat / 768, k = flat % 768;
        const float* xp = W_x + (size_t)k * 56;
        float acc = 0.f;
        #pragma unroll
        for (int r = 0; r < 24; ++r)
            acc = fmaf(xp[r], W_dt[(size_t)r * 768 + j], acc);
        unsigned short h = f2bf(acc);
        btc_hi[(size_t)(32 + j) * 768 + k] = h;
        btc_lo[(size_t)(32 + j) * 768 + k] = f2bf(acc - bf2f(h));
    } else if (blk < 4082) {
        const int flat = (blk - 3696) * 256 + tid;
        if (flat < 384 * 256) {
            const int n = flat >> 8, k = flat & 255;
            float val = 0.f;
            if (n < 192) { if (k < 128) val = W_ev[(size_t)k * 192 + n]; }
            else         { if (k >= 128) val = W_rgb[(size_t)(k - 128) * 192 + (n - 192)]; }
            unsigned short h = f2bf(val);
            wct_hi[flat] = h;
            wct_lo[flat] = f2bf(val - bf2f(h));
        } else if (flat < 384 * 256 + 384) {
            const int i = flat - 384 * 256;
            biascat[i] = (i < 192) ? b_ev[i] : b_rgb[i - 192];
        }
    } else if (blk < 5106) {
        const int idx = (blk - 4082) * 1024 + tid * 4;  // 4096*256 elems
        const int m = idx >> 8, kk = idx & 255;
        #pragma unroll
        for (int q = 0; q < 4; ++q) {
            int k = kk + q;
            float val = (k < 128) ? ev[(size_t)m * 128 + k] : rgb[(size_t)m * 128 + k - 128];
            apk[(size_t)m * 256 + k] = packf(val);
        }
    } else if (blk < 5682) {
        // wpd = W_proj row-major hi/lo split (Bt for the W_pi GEMM)
        const int flat = (blk - 5106) * 256 + tid;      // 384*384
        float val = W_proj[flat];
        unsigned short h = f2bf(val);
        wpd_hi[flat] = h;
        wpd_lo[flat] = f2bf(val - bf2f(h));
    } else {
        // bias_pi[j] = sum_i b_proj[i] * W_in[i][j]
        const int j = (blk - 5682) * 256 + tid;         // 1536
        float acc = 0.f;
        for (int i = 0; i < 384; ++i)
            acc = fmaf(b_proj[i], W_in[(size_t)i * 1536 + j], acc);
        bias_pi[j] = acc;
    }
}

// ---------------- LN over 384: sums embed split-partials + bias, writes hi/lo planes ----------------
__global__ __launch_bounds__(256)
void ln2(const float* __restrict__ ep0, const float* __restrict__ ep1,
         const float* __restrict__ biascat,
         const float* __restrict__ g, const float* __restrict__ b,
         unsigned short* __restrict__ hi, unsigned short* __restrict__ lo)
{
    const int lane = threadIdx.x & 63;
    const int row = blockIdx.x * 4 + (threadIdx.x >> 6);
    const float* p0 = ep0 + (size_t)row * 384;
    const float* p1 = ep1 + (size_t)row * 384;
    unsigned short* ph = hi + (size_t)row * 384;
    unsigned short* pl = lo + (size_t)row * 384;
    float v[6];
    #pragma unroll
    for (int i = 0; i < 6; ++i) {
        int c = i * 64 + lane;
        v[i] = p0[c] + p1[c] + biascat[c];
    }
    float s = v[0] + v[1] + v[2] + v[3] + v[4] + v[5];
    #pragma unroll
    for (int m = 32; m >= 1; m >>= 1) s += __shfl_xor(s, m);
    const float mu = s * (1.f / 384.f);
    float q = 0.f;
    #pragma unroll
    for (int i = 0; i < 6; ++i) { float dv = v[i] - mu; q = fmaf(dv, dv, q); }
    #pragma unroll
    for (int m = 32; m >= 1; m >>= 1) q += __shfl_xor(q, m);
    const float inv = 1.f / sqrtf(q * (1.f / 384.f) + 1e-5f);
    #pragma unroll
    for (int i = 0; i < 6; ++i) {
        int c = i * 64 + lane;
        float o = (v[i] - mu) * inv * g[c] + b[c];
        unsigned short h = f2bf(o);
        ph[c] = h;
        pl[c] = f2bf(o - bf2f(h));
    }
}

// ------- depthwise causal conv(4) + SiLU -> packed u; u_pre is [4096][768] -------
__global__ __launch_bounds__(256)
void conv_pack(const float* __restrict__ u_pre, const float* __restrict__ conv_w,
               const float* __restrict__ conv_b, unsigned int* __restrict__ upk)
{
    const int d = blockIdx.x * 256 + threadIdx.x;
    const int t0 = blockIdx.z * L_SEQ + blockIdx.y * 16;
    const float w0 = conv_w[d * 4 + 0], w1 = conv_w[d * 4 + 1];
    const float w2 = conv_w[d * 4 + 2], w3 = conv_w[d * 4 + 3];
    const float cb = conv_b[d];
    const float* xp = u_pre + (size_t)t0 * 768 + d;
    float x1, x2, x3;
    if (blockIdx.y == 0) { x1 = x2 = x3 = 0.f; }
    else {
        x1 = xp[-1 * 768];
        x2 = xp[-2 * 768];
        x3 = xp[-3 * 768];
    }
    unsigned int* op = upk + (size_t)t0 * 768 + d;
    #pragma unroll 4
    for (int i = 0; i < 16; ++i) {
        float cur = xp[i * 768];
        float a = cb;
        a = fmaf(x3, w0, a);
        a = fmaf(x2, w1, a);
        a = fmaf(x1, w2, a);
        a = fmaf(cur, w3, a);
        op[i * 768] = packf(silu_f(a));
        x3 = x2; x2 = x1; x1 = cur;
    }
}

// ---------------- combine fused-GEMM split partials: bc + softplus(delta) ----------------
__global__ __launch_bounds__(256)
void combine_fused(const float* __restrict__ P0, const float* __restrict__ P1,
                   const float* __restrict__ b_dt,
                   float* __restrict__ bc, float* __restrict__ delta)
{
    const int g = blockIdx.x * 256 + threadIdx.x;   // 4096*200
    const int m = g / 200, c0 = (g % 200) * 4;
    const float* a = P0 + (size_t)m * 800 + c0;
    const float* bb = P1 + (size_t)m * 800 + c0;
    float4 s0 = *(const float4*)a;
    float4 s1 = *(const float4*)bb;
    float sv[4] = {s0.x + s1.x, s0.y + s1.y, s0.z + s1.z, s0.w + s1.w};
    #pragma unroll
    for (int j = 0; j < 4; ++j) {
        int col = c0 + j;
        if (col < 32) {
            bc[(size_t)m * 32 + col] = sv[j];
        } else {
            float o = sv[j] + b_dt[col - 32];
            delta[(size_t)m * 768 + col - 32] = fmaxf(o, 0.f) + log1pf(expf(-fabsf(o)));
        }
    }
}

// ---------------- combine out-GEMM split partials -> d_out ----------------
__global__ __launch_bounds__(256)
void combine_out(const float* __restrict__ PA, const float* __restrict__ PB,
                 float* __restrict__ out)
{
    const int g = blockIdx.x * 256 + threadIdx.x;   // 4096*96
    const size_t o = (size_t)g * 4;
    float4 a0 = *(const float4*)(PA + o);
    float4 a1 = *(const float4*)(PA + 1572864 + o);
    float4 a2 = *(const float4*)(PB + o);
    float4 a3 = *(const float4*)(PB + 1572864 + o);
    float4 r;
    r.x = a0.x + a1.x + a2.x + a3.x;
    r.y = a0.y + a1.y + a2.y + a3.y;
    r.z = a0.z + a1.z + a2.z + a3.z;
    r.w = a0.w + a1.w + a2.w + a3.w;
    *(float4*)(out + o) = r;
}

// ---------------- chunked selective scan ----------------
__global__ __launch_bounds__(256)
void scan_a2(const float* __restrict__ delta, const unsigned int* __restrict__ upk,
             const float* __restrict__ bc, const float* __restrict__ A_log,
             float* __restrict__ dsum_out, float* __restrict__ Bc)
{
    __shared__ float Bsh[CLEN][16];
    const int tid = threadIdx.x;
    const int d = blockIdx.x * 256 + tid;
    const int c = blockIdx.y, b = blockIdx.z;
    const int row0 = b * L_SEQ + c * CLEN;
    {
        int t = tid >> 4, n = tid & 15;
        Bsh[t][n] = bc[(size_t)(row0 + t) * 32 + n];
    }
    float AL2[16];
    {
        const float* ap = A_log + d * 16;
        #pragma unroll
        for (int n = 0; n < 16; ++n)
            AL2[n] = -__expf(ap[n]) * 1.44269504f;
    }
    __syncthreads();
    float h[16];
    #pragma unroll
    for (int n = 0; n < 16; ++n) h[n] = 0.f;
    float dsum = 0.f;
    const float* dp = delta + (size_t)row0 * 768 + d;
    const unsigned int* up = upk + (size_t)row0 * 768 + d;
    #pragma unroll 4
    for (int t = 0; t < CLEN; ++t) {
        float dt = dp[t * 768];
        float ut = unpackf(up[t * 768]);
        float du = dt * ut;
        dsum += dt;
        #pragma unroll
        for (int n = 0; n < 16; ++n) {
            float dA = exp2_fast(dt * AL2[n]);
            h[n] = fmaf(dA, h[n], du * Bsh[t][n]);
        }
    }
    dsum_out[(size_t)(b * 768 + d) * NCHUNK + c] = dsum;
    float* bcp = Bc + (((size_t)(b * 768 + d)) * NCHUNK + c) * 16;
    #pragma unroll
    for (int n = 0; n < 16; ++n) bcp[n] = h[n];
}

__global__ __launch_bounds__(256)
void scan_b2(const float* __restrict__ dsum, const float* __restrict__ A_log,
             float* __restrict__ BcHin)
{
    const size_t flat = (size_t)blockIdx.x * 256 + threadIdx.x;  // 0..49151
    const size_t bd = flat >> 4;
    const int n = (int)(flat & 15);
    const int d = (int)(bd % 768);
    const float AL2 = -__expf(A_log[d * 16 + n]) * 1.44269504f;
    const float* dsp = dsum + bd * NCHUNK;
    const size_t base = bd * (NCHUNK * 16) + n;
    float h = 0.f;
    for (int c = 0; c < NCHUNK; ++c) {
        size_t i = base + (size_t)c * 16;
        float a = exp2_fast(AL2 * dsp[c]);
        float bb = BcHin[i];
        BcHin[i] = h;
        h = fmaf(a, h, bb);
    }
}

__global__ __launch_bounds__(256)
void scan_c2(float* __restrict__ delta, const unsigned int* __restrict__ upk,
             const float* __restrict__ bc, const float* __restrict__ A_log,
             const float* __restrict__ Hin, const float* __restrict__ D_skip,
             const float* __restrict__ res)   // [4096][768]; y packed over delta
{
    __shared__ float Bsh[CLEN][16];
    __shared__ float Csh[CLEN][16];
    const int tid = threadIdx.x;
    const int d = blockIdx.x * 256 + tid;
    const int c = blockIdx.y, b = blockIdx.z;
    const int row0 = b * L_SEQ + c * CLEN;
    {
        int t = tid >> 4, n = tid & 15;
        const float* xp = bc + (size_t)(row0 + t) * 32;
        Bsh[t][n] = xp[n];
        Csh[t][n] = xp[16 + n];
    }
    float AL2[16];
    {
        const float* ap = A_log + d * 16;
        #pragma unroll
        for (int n = 0; n < 16; ++n)
            AL2[n] = -__expf(ap[n]) * 1.44269504f;
    }
    float h[16];
    {
        const float* hp = Hin + (((size_t)(b * 768 + d)) * NCHUNK + c) * 16;
        #pragma unroll
        for (int n = 0; n < 16; ++n) h[n] = hp[n];
    }
    const float Ds = D_skip[d];
    __syncthreads();
    float* dp = delta + (size_t)row0 * 768 + d;
    const unsigned int* up = upk + (size_t)row0 * 768 + d;
    const float* rp = res + (size_t)row0 * 768 + d;
    #pragma unroll 4
    for (int t = 0; t < CLEN; ++t) {
        float dt = dp[t * 768];
        float ut = unpackf(up[t * 768]);
        float du = dt * ut;
        float y = 0.f;
        #pragma unroll
        for (int n = 0; n < 16; ++n) {
            float dA = exp2_fast(dt * AL2[n]);
            h[n] = fmaf(dA, h[n], du * Bsh[t][n]);
            y = fmaf(h[n], Csh[t][n], y);
        }
        float rr = rp[t * 768];
        float gy = fmaf(ut, Ds, y) * silu_f(rr);
        dp[t * 768] = __builtin_bit_cast(float, packf(gy));
    }
}

extern "C" void kernel_launch(void* const* d_in, const int* in_sizes, int n_in,
                              void* d_out, int out_size, void* d_ws, size_t ws_size,
                              hipStream_t stream)
{
    const float* ev     = (const float*)d_in[0];
    const float* rgb    = (const float*)d_in[1];
    const float* W_ev   = (const float*)d_in[2];
    const float* b_ev   = (const float*)d_in[3];
    const float* W_rgb  = (const float*)d_in[4];
    const float* b_rgb  = (const float*)d_in[5];
    const float* ln_g   = (const float*)d_in[6];
    const float* ln_b   = (const float*)d_in[7];
    const float* W_proj = (const float*)d_in[8];
    const float* b_proj = (const float*)d_in[9];
    const float* W_in   = (const float*)d_in[10];
    const float* conv_w = (const float*)d_in[11];
    const float* conv_b = (const float*)d_in[12];
    const float* W_x    = (const float*)d_in[13];
    const float* W_dt   = (const float*)d_in[14];
    const float* b_dt   = (const float*)d_in[15];
    const float* A_log  = (const float*)d_in[16];
    const float* D_skip = (const float*)d_in[17];
    const float* W_out  = (const float*)d_in[18];
    float* out = (float*)d_out;

    // workspace (float units), total 16,877,440 fl = 67.5 MB
    float* ws = (float*)d_ws;
    const size_t O0 = 0;            // res [4096][768]; apk (prep->embed)
    const size_t O1 = 3145728;      // u_pre / embed partials / fused P0 / out partials z0,z1
    const size_t O2 = 6422528;      // upk; earlier xf planes + wpi planes
    const size_t O3 = 9568256;      // delta; earlier wtp,wpd,wti,btc
    const size_t O4 = 12713984;     // fused P1 / dsum+BcHin / out partials z2,z3
    const size_t O5 = 16056320;     // persistent small: wct, biascat, bias_pi, wto, bc

    float* res   = ws + O0;
    unsigned int* apk = (unsigned int*)(ws + O0);
    float* u_pre = ws + O1;
    float* ep0   = ws + O1;
    float* ep1   = ws + O1 + 1572864;
    float* P0    = ws + O1;
    float* outPA = ws + O1;
    unsigned int* upk = (unsigned int*)(ws + O2);
    unsigned short* xfh = (unsigned short*)(ws + O2);
    unsigned short* xfl = xfh + 1572864;
    unsigned short* wpi_hi = (unsigned short*)(ws + O2 + 1572864);
    unsigned short* wpi_lo = wpi_hi + 589824;
    float* delta = ws + O3;
    unsigned short* wtp_hi = (unsigned short*)(ws + O3);
    unsigned short* wtp_lo = wtp_hi + 147456;
    unsigned short* wpd_hi = wtp_lo + 147456;
    unsigned short* wpd_lo = wpd_hi + 147456;
    unsigned short* wti_hi = wpd_lo + 147456;
    unsigned short* wti_lo = wti_hi + 589824;
    unsigned short* btc_hi = (unsigned short*)(ws + O3 + 884736);
    unsigned short* btc_lo = btc_hi + 688128;
    float* P1    = ws + O4;
    float* dsum  = ws + O4;
    float* BcHin = ws + O4 + 196608;
    float* outPB = ws + O4;
    unsigned short* wct_hi = (unsigned short*)(ws + O5);
    unsigned short* wct_lo = wct_hi + 98304;
    float* biascat = ws + O5 + 98304;
    float* bias_pi = ws + O5 + 98688;
    unsigned short* wto_hi = (unsigned short*)(ws + O5 + 100224);
    unsigned short* wto_lo = wto_hi + 589824;
    float* bc    = ws + O5 + 690048;

    dim3 blk(256);

    // prep: all weight conversions + W_comb + wpd + bias_pi + embed pack
    prep_all<<<5688, blk, 0, stream>>>(
        W_proj, W_in, W_out, W_x, W_dt, b_proj, W_ev, W_rgb, b_ev, b_rgb, ev, rgb,
        wtp_hi, wtp_lo, wti_hi, wti_lo, wto_hi, wto_lo,
        btc_hi, btc_lo, wct_hi, wct_lo, wpd_hi, wpd_lo, biascat, bias_pi, apk);

    // embed: [ev|rgb] @ blockdiag, split-K x2 -> f32 partials
    gemm_bf3<true, 3, 2><<<dim3(3, 32, 2), blk, 0, stream>>>(
        nullptr, nullptr, apk, 256, wct_hi, wct_lo, nullptr,
        ep0, ep1, nullptr, nullptr, 128, 256, 384);
    // W_pi^T = W_in^T @ W_proj^T  (MFMA, hi/lo out) [1536][384]
    gemm_bf3<false, 1, 1><<<dim3(3, 12), blk, 0, stream>>>(
        wti_hi, wti_lo, nullptr, 384, wpd_hi, wpd_lo, nullptr,
        nullptr, nullptr, wpi_hi, wpi_lo, 384, 384, 384);
    // LN: combine embed partials + bias, write xf planes
    ln2<<<1024, blk, 0, stream>>>(ep0, ep1, biascat, ln_g, ln_b, xfh, xfl);
    // big GEMM: LN_out @ W_pi + bias_pi -> u_pre | res
    gemm_bf3<false, 4, 1><<<dim3(12, 32), blk, 0, stream>>>(
        xfh, xfl, nullptr, 384, wpi_hi, wpi_lo, bias_pi,
        u_pre, res, nullptr, nullptr, 384, 384, 1536);
    // conv + silu -> packed u
    conv_pack<<<dim3(3, 64, 4), blk, 0, stream>>>(u_pre, conv_w, conv_b, upk);
    // fused x_dbl B/C + delta-pre GEMM, split-K x2 -> partials
    gemm_bf3<true, 3, 2><<<dim3(7, 32, 2), blk, 0, stream>>>(
        nullptr, nullptr, upk, 768, btc_hi, btc_lo, nullptr,
        P0, P1, nullptr, nullptr, 384, 768, 800);
    combine_fused<<<3200, blk, 0, stream>>>(P0, P1, b_dt, bc, delta);
    // chunked scan
    scan_a2<<<dim3(3, NCHUNK, 4), blk, 0, stream>>>(delta, upk, bc, A_log, dsum, BcHin);
    scan_b2<<<192, blk, 0, stream>>>(dsum, A_log, BcHin);
    scan_c2<<<dim3(3, NCHUNK, 4), blk, 0, stream>>>(delta, upk, bc, A_log, BcHin, D_skip, res);
    // out GEMM split-K x4 -> partials -> combine
    gemm_bf3<true, 3, 4><<<dim3(3, 32, 4), blk, 0, stream>>>(
        nullptr, nullptr, (const unsigned int*)delta, 768, wto_hi, wto_lo, nullptr,
        outPA, outPB, nullptr, nullptr, 192, 768, 384);
    combine_out<<<1536, blk, 0, stream>>>(outPA, outPB, out);
}

// Round 10
// 245.022 us; speedup vs baseline: 1.2184x; 1.2184x over previous
//
#include <hip/hip_runtime.h>
#include <cstddef>
#include <cstdint>

#define L_SEQ 1024
#define NCHUNK 64
#define CLEN 16

typedef __bf16 bf16x8 __attribute__((ext_vector_type(8)));
typedef float f32x4 __attribute__((ext_vector_type(4)));

__device__ __forceinline__ float silu_f(float x) {
    return x / (1.f + __expf(-x));
}
__device__ __forceinline__ float exp2_fast(float x) { return exp2f(x); }

__device__ __forceinline__ unsigned short f2bf(float x) {
    union { float f; unsigned int u; } v; v.f = x;
    unsigned int r = (v.u + 0x7fffu + ((v.u >> 16) & 1u)) >> 16;
    return (unsigned short)r;
}
__device__ __forceinline__ float bf2f(unsigned short h) {
    union { float f; unsigned int u; } v; v.u = ((unsigned int)h) << 16;
    return v.f;
}
__device__ __forceinline__ unsigned int packf(float x) {
    unsigned short h = f2bf(x);
    unsigned short l = f2bf(x - bf2f(h));
    return ((unsigned int)h << 16) | (unsigned int)l;
}
__device__ __forceinline__ float unpackf(unsigned int pk) {
    return bf2f((unsigned short)(pk >> 16)) + bf2f((unsigned short)(pk & 0xffffu));
}

// ---------------- bf16x3 MFMA GEMM: 128x128 tile, BK=32, 4 waves ----------------
// Single-buffered LDS (40KB). Per K-step: store_lds -> barrier -> issue next loads
// -> MFMA -> barrier. Split-K via blockIdx.z. XCD swizzle when per-z grid %8==0.
// EPI 1: bf16 hi/lo planes (ldc=Nw). EPI 3: raw f32 partial (cols<Nw) to split-partial
// buffers Cf/Cf2 (half the z's each). EPI 4: +bias; cols<768 -> Cf, else Cf2.
// EPI 6: softplus(o + bias[nn]) -> Cf with ldc=Nw.
template<bool APK, int EPI, int SPLITS>
__global__ __launch_bounds__(256)
void gemm_bf3(const unsigned short* __restrict__ Ahi,
              const unsigned short* __restrict__ Alo,
              const unsigned int* __restrict__ Apk, int lda,
              const unsigned short* __restrict__ Bthi,
              const unsigned short* __restrict__ Btlo,
              const float* __restrict__ bias,
              float* __restrict__ Cf, float* __restrict__ Cf2,
              unsigned short* __restrict__ Chi, unsigned short* __restrict__ Clo,
              int Ks, int Ktot, int Nw)
{
    __shared__ unsigned short As[2][128][40];   // [plane][row][k]
    __shared__ unsigned short Bs[2][128][40];
    const int tid = threadIdx.x;
    const int lane = tid & 63;
    const int wave = tid >> 6;
    const int wm = wave >> 1, wn = wave & 1;

    const int gx = gridDim.x;
    const int nwg = gx * gridDim.y;
    const int lin = blockIdx.y * gx + blockIdx.x;
    const int swz = ((nwg & 7) == 0) ? ((lin & 7) * (nwg >> 3) + (lin >> 3)) : lin;
    const int m0 = (swz / gx) * 128, n0 = (swz % gx) * 128;
    const int z = (SPLITS > 1) ? blockIdx.z : 0;
    const int kbeg = z * Ks;

    const int srow = tid >> 1, sko = (tid & 1) * 16;

    f32x4 acc[4][4];
    #pragma unroll
    for (int i = 0; i < 4; ++i)
        #pragma unroll
        for (int j = 0; j < 4; ++j) {
            f32x4 zz = {0.f, 0.f, 0.f, 0.f};
            acc[i][j] = zz;
        }

    const size_t aoff = (size_t)(m0 + srow) * lda + sko;
    const size_t boff = (size_t)(n0 + srow) * Ktot + sko;

    uint4 ra[4], rb[4];

    auto load_regs = [&](int k0) {
        if constexpr (APK) {
            const unsigned int* ap = Apk + aoff + k0;
            ra[0] = *(const uint4*)(ap);
            ra[1] = *(const uint4*)(ap + 4);
            ra[2] = *(const uint4*)(ap + 8);
            ra[3] = *(const uint4*)(ap + 12);
        } else {
            ra[0] = *(const uint4*)(Ahi + aoff + k0);
            ra[1] = *(const uint4*)(Ahi + aoff + k0 + 8);
            ra[2] = *(const uint4*)(Alo + aoff + k0);
            ra[3] = *(const uint4*)(Alo + aoff + k0 + 8);
        }
        rb[0] = *(const uint4*)(Bthi + boff + k0);
        rb[1] = *(const uint4*)(Bthi + boff + k0 + 8);
        rb[2] = *(const uint4*)(Btlo + boff + k0);
        rb[3] = *(const uint4*)(Btlo + boff + k0 + 8);
    };

    auto store_lds = [&]() {
        uint4 h0, h1, l0, l1;
        if constexpr (APK) {
            uint4 p0 = ra[0], p1 = ra[1], p2 = ra[2], p3 = ra[3];
            h0.x = (p0.x >> 16) | (p0.y & 0xffff0000u);
            h0.y = (p0.z >> 16) | (p0.w & 0xffff0000u);
            h0.z = (p1.x >> 16) | (p1.y & 0xffff0000u);
            h0.w = (p1.z >> 16) | (p1.w & 0xffff0000u);
            h1.x = (p2.x >> 16) | (p2.y & 0xffff0000u);
            h1.y = (p2.z >> 16) | (p2.w & 0xffff0000u);
            h1.z = (p3.x >> 16) | (p3.y & 0xffff0000u);
            h1.w = (p3.z >> 16) | (p3.w & 0xffff0000u);
            l0.x = (p0.x & 0xffffu) | (p0.y << 16);
            l0.y = (p0.z & 0xffffu) | (p0.w << 16);
            l0.z = (p1.x & 0xffffu) | (p1.y << 16);
            l0.w = (p1.z & 0xffffu) | (p1.w << 16);
            l1.x = (p2.x & 0xffffu) | (p2.y << 16);
            l1.y = (p2.z & 0xffffu) | (p2.w << 16);
            l1.z = (p3.x & 0xffffu) | (p3.y << 16);
            l1.w = (p3.z & 0xffffu) | (p3.w << 16);
        } else {
            h0 = ra[0]; h1 = ra[1]; l0 = ra[2]; l1 = ra[3];
        }
        *(uint4*)&As[0][srow][sko]     = h0;
        *(uint4*)&As[0][srow][sko + 8] = h1;
        *(uint4*)&As[1][srow][sko]     = l0;
        *(uint4*)&As[1][srow][sko + 8] = l1;
        *(uint4*)&Bs[0][srow][sko]     = rb[0];
        *(uint4*)&Bs[0][srow][sko + 8] = rb[1];
        *(uint4*)&Bs[1][srow][sko]     = rb[2];
        *(uint4*)&Bs[1][srow][sko + 8] = rb[3];
    };

    const int fr = lane & 15, kq = lane >> 4;
    const int kend = kbeg + Ks;

    load_regs(kbeg);
    for (int k0 = kbeg; k0 < kend; k0 += 32) {
        store_lds();
        __syncthreads();
        if (k0 + 32 < kend) load_regs(k0 + 32);
        {
            bf16x8 aH[4], aL[4];
            #pragma unroll
            for (int i = 0; i < 4; ++i) {
                aH[i] = *(const bf16x8*)&As[0][wm * 64 + i * 16 + fr][kq * 8];
                aL[i] = *(const bf16x8*)&As[1][wm * 64 + i * 16 + fr][kq * 8];
            }
            #pragma unroll
            for (int j = 0; j < 4; ++j) {
                bf16x8 bH = *(const bf16x8*)&Bs[0][wn * 64 + j * 16 + fr][kq * 8];
                bf16x8 bL = *(const bf16x8*)&Bs[1][wn * 64 + j * 16 + fr][kq * 8];
                #pragma unroll
                for (int i = 0; i < 4; ++i)
                    acc[i][j] = __builtin_amdgcn_mfma_f32_16x16x32_bf16(aH[i], bH, acc[i][j], 0, 0, 0);
                #pragma unroll
                for (int i = 0; i < 4; ++i)
                    acc[i][j] = __builtin_amdgcn_mfma_f32_16x16x32_bf16(aL[i], bH, acc[i][j], 0, 0, 0);
                #pragma unroll
                for (int i = 0; i < 4; ++i)
                    acc[i][j] = __builtin_amdgcn_mfma_f32_16x16x32_bf16(aH[i], bL, acc[i][j], 0, 0, 0);
            }
        }
        __syncthreads();
    }

    // epilogue
    float* myP = nullptr;
    if constexpr (EPI == 3) {
        float* base = (2 * z >= SPLITS) ? Cf2 : Cf;
        int sub = z - ((2 * z >= SPLITS) ? SPLITS / 2 : 0);
        myP = base + (size_t)sub * (size_t)(gridDim.y * 128) * Nw;
    }
    const int col = lane & 15, rq = lane >> 4;
    #pragma unroll
    for (int j = 0; j < 4; ++j) {
        int nn = n0 + wn * 64 + j * 16 + col;
        float bv = 0.f;
        if constexpr (EPI == 1 || EPI == 4 || EPI == 6) { if (bias) bv = bias[nn]; }
        #pragma unroll
        for (int i = 0; i < 4; ++i) {
            int mb = m0 + wm * 64 + i * 16 + rq * 4;
            #pragma unroll
            for (int r = 0; r < 4; ++r) {
                float o = acc[i][j][r] + bv;
                if constexpr (EPI == 1) {
                    unsigned short h = f2bf(o);
                    Chi[(size_t)(mb + r) * Nw + nn] = h;
                    Clo[(size_t)(mb + r) * Nw + nn] = f2bf(o - bf2f(h));
                } else if constexpr (EPI == 3) {
                    if (nn < Nw) myP[(size_t)(mb + r) * Nw + nn] = o;
                } else if constexpr (EPI == 4) {
                    if (nn < 768) Cf[(size_t)(mb + r) * 768 + nn] = o;
                    else          Cf2[(size_t)(mb + r) * 768 + (nn - 768)] = o;
                } else if constexpr (EPI == 6) {
                    float sp = fmaxf(o, 0.f) + log1pf(expf(-fabsf(o)));
                    Cf[(size_t)(mb + r) * Nw + nn] = sp;
                }
            }
        }
    }
}

// ---------------- fused one-shot prep ----------------
__device__ __forceinline__ void wcvt_body(const float* __restrict__ W,
                                          unsigned short* __restrict__ Thi,
                                          unsigned short* __restrict__ Tlo,
                                          int K, int N, int nx, int local, int tid,
                                          float* t /* [32][33] */)
{
    const int n0 = (local % nx) * 32, k0 = (local / nx) * 32;
    const int r = tid >> 3, c4 = (tid & 7) * 4;
    float4 v = *(const float4*)(W + (size_t)(k0 + r) * N + n0 + c4);
    t[r * 33 + c4 + 0] = v.x; t[r * 33 + c4 + 1] = v.y;
    t[r * 33 + c4 + 2] = v.z; t[r * 33 + c4 + 3] = v.w;
    __syncthreads();
    unsigned short hs[4], ls[4];
    #pragma unroll
    for (int j = 0; j < 4; ++j) {
        float x = t[(c4 + j) * 33 + r];
        hs[j] = f2bf(x);
        ls[j] = f2bf(x - bf2f(hs[j]));
    }
    size_t o = (size_t)(n0 + r) * K + k0 + c4;
    uint2 hv, lv;
    hv.x = (unsigned)hs[0] | ((unsigned)hs[1] << 16);
    hv.y = (unsigned)hs[2] | ((unsigned)hs[3] << 16);
    lv.x = (unsigned)ls[0] | ((unsigned)ls[1] << 16);
    lv.y = (unsigned)ls[2] | ((unsigned)ls[3] << 16);
    *(uint2*)(Thi + o) = hv;
    *(uint2*)(Tlo + o) = lv;
}

// Regions: [0,576) wti; [576,864) wto; [864,1250) wct+biascat; [1250,2274) embed pack;
// [2274,2850) wpd; [2850,2856) bias_pi; [2856,3240) wx56t; [3240,3336) wdtT.
__global__ __launch_bounds__(256)
void prep_all(const float* __restrict__ W_in, const float* __restrict__ W_out,
              const float* __restrict__ W_x, const float* __restrict__ W_dt,
              const float* __restrict__ W_proj, const float* __restrict__ b_proj,
              const float* __restrict__ W_ev, const float* __restrict__ W_rgb,
              const float* __restrict__ b_ev, const float* __restrict__ b_rgb,
              const float* __restrict__ ev, const float* __restrict__ rgb,
              unsigned short* __restrict__ wti_hi, unsigned short* __restrict__ wti_lo,
              unsigned short* __restrict__ wto_hi, unsigned short* __restrict__ wto_lo,
              unsigned short* __restrict__ wct_hi, unsigned short* __restrict__ wct_lo,
              unsigned short* __restrict__ wpd_hi, unsigned short* __restrict__ wpd_lo,
              unsigned short* __restrict__ wx56t_hi, unsigned short* __restrict__ wx56t_lo,
              unsigned short* __restrict__ wdtT_hi, unsigned short* __restrict__ wdtT_lo,
              float* __restrict__ biascat, float* __restrict__ bias_pi,
              unsigned int* __restrict__ apk)
{
    __shared__ float t[32 * 33];
    const int blk = blockIdx.x;
    const int tid = threadIdx.x;
    if (blk < 576) {
        wcvt_body(W_in, wti_hi, wti_lo, 384, 1536, 48, blk, tid, t);
    } else if (blk < 864) {
        wcvt_body(W_out, wto_hi, wto_lo, 768, 384, 12, blk - 576, tid, t);
    } else if (blk < 1250) {
        const int flat = (blk - 864) * 256 + tid;
        if (flat < 384 * 256) {
            const int n = flat >> 8, k = flat & 255;
            float val = 0.f;
            if (n < 192) { if (k < 128) val = W_ev[(size_t)k * 192 + n]; }
            else         { if (k >= 128) val = W_rgb[(size_t)(k - 128) * 192 + (n - 192)]; }
            unsigned short h = f2bf(val);
            wct_hi[flat] = h;
            wct_lo[flat] = f2bf(val - bf2f(h));
        } else if (flat < 384 * 256 + 384) {
            const int i = flat - 384 * 256;
            biascat[i] = (i < 192) ? b_ev[i] : b_rgb[i - 192];
        }
    } else if (blk < 2274) {
        const int idx = (blk - 1250) * 1024 + tid * 4;  // 4096*256 elems
        const int m = idx >> 8, kk = idx & 255;
        #pragma unroll
        for (int q = 0; q < 4; ++q) {
            int k = kk + q;
            float val = (k < 128) ? ev[(size_t)m * 128 + k] : rgb[(size_t)m * 128 + k - 128];
            apk[(size_t)m * 256 + k] = packf(val);
        }
    } else if (blk < 2850) {
        // wpd = W_proj row-major hi/lo split (Bt for the W_pi GEMM)
        const int flat = (blk - 2274) * 256 + tid;      // 384*384
        float val = W_proj[flat];
        unsigned short h = f2bf(val);
        wpd_hi[flat] = h;
        wpd_lo[flat] = f2bf(val - bf2f(h));
    } else if (blk < 2856) {
        // bias_pi[j] = sum_i b_proj[i] * W_in[i][j]
        const int j = (blk - 2850) * 256 + tid;         // 1536
        float acc = 0.f;
        for (int i = 0; i < 384; ++i)
            acc = fmaf(b_proj[i], W_in[(size_t)i * 1536 + j], acc);
        bias_pi[j] = acc;
    } else if (blk < 3240) {
        // wx56t[128][768]: rows 0..55 = W_x[:, :56]^T, rows 56..127 = 0
        const int flat = (blk - 2856) * 256 + tid;      // 128*768
        const int r = flat / 768, k = flat % 768;
        float val = (r < 56) ? W_x[(size_t)k * 56 + r] : 0.f;
        unsigned short h = f2bf(val);
        wx56t_hi[(size_t)r * 768 + k] = h;
        wx56t_lo[(size_t)r * 768 + k] = f2bf(val - bf2f(h));
    } else {
        // wdtT[768][32]: cols 0..23 = W_dt^T, cols 24..31 = 0
        const int flat = (blk - 3240) * 256 + tid;      // 768*32
        const int j = flat >> 5, kk = flat & 31;
        float val = (kk < 24) ? W_dt[(size_t)kk * 768 + j] : 0.f;
        unsigned short h = f2bf(val);
        wdtT_hi[(size_t)j * 32 + kk] = h;
        wdtT_lo[(size_t)j * 32 + kk] = f2bf(val - bf2f(h));
    }
}

// ---------------- LN over 384: sums embed split-partials + bias, writes hi/lo planes ----------------
__global__ __launch_bounds__(256)
void ln2(const float* __restrict__ ep0, const float* __restrict__ ep1,
         const float* __restrict__ biascat,
         const float* __restrict__ g, const float* __restrict__ b,
         unsigned short* __restrict__ hi, unsigned short* __restrict__ lo)
{
    const int lane = threadIdx.x & 63;
    const int row = blockIdx.x * 4 + (threadIdx.x >> 6);
    const float* p0 = ep0 + (size_t)row * 384;
    const float* p1 = ep1 + (size_t)row * 384;
    unsigned short* ph = hi + (size_t)row * 384;
    unsigned short* pl = lo + (size_t)row * 384;
    float v[6];
    #pragma unroll
    for (int i = 0; i < 6; ++i) {
        int c = i * 64 + lane;
        v[i] = p0[c] + p1[c] + biascat[c];
    }
    float s = v[0] + v[1] + v[2] + v[3] + v[4] + v[5];
    #pragma unroll
    for (int m = 32; m >= 1; m >>= 1) s += __shfl_xor(s, m);
    const float mu = s * (1.f / 384.f);
    float q = 0.f;
    #pragma unroll
    for (int i = 0; i < 6; ++i) { float dv = v[i] - mu; q = fmaf(dv, dv, q); }
    #pragma unroll
    for (int m = 32; m >= 1; m >>= 1) q += __shfl_xor(q, m);
    const float inv = 1.f / sqrtf(q * (1.f / 384.f) + 1e-5f);
    #pragma unroll
    for (int i = 0; i < 6; ++i) {
        int c = i * 64 + lane;
        float o = (v[i] - mu) * inv * g[c] + b[c];
        unsigned short h = f2bf(o);
        ph[c] = h;
        pl[c] = f2bf(o - bf2f(h));
    }
}

// ------- depthwise causal conv(4) + SiLU -> packed u; u_pre is [4096][768] -------
__global__ __launch_bounds__(256)
void conv_pack(const float* __restrict__ u_pre, const float* __restrict__ conv_w,
               const float* __restrict__ conv_b, unsigned int* __restrict__ upk)
{
    const int d = blockIdx.x * 256 + threadIdx.x;
    const int t0 = blockIdx.z * L_SEQ + blockIdx.y * 16;
    const float w0 = conv_w[d * 4 + 0], w1 = conv_w[d * 4 + 1];
    const float w2 = conv_w[d * 4 + 2], w3 = conv_w[d * 4 + 3];
    const float cb = conv_b[d];
    const float* xp = u_pre + (size_t)t0 * 768 + d;
    float x1, x2, x3;
    if (blockIdx.y == 0) { x1 = x2 = x3 = 0.f; }
    else {
        x1 = xp[-1 * 768];
        x2 = xp[-2 * 768];
        x3 = xp[-3 * 768];
    }
    unsigned int* op = upk + (size_t)t0 * 768 + d;
    #pragma unroll 4
    for (int i = 0; i < 16; ++i) {
        float cur = xp[i * 768];
        float a = cb;
        a = fmaf(x3, w0, a);
        a = fmaf(x2, w1, a);
        a = fmaf(x1, w2, a);
        a = fmaf(cur, w3, a);
        op[i * 768] = packf(silu_f(a));
        x3 = x2; x2 = x1; x1 = cur;
    }
}

// ---- combine GEMM1 split partials: cols 0..23 -> packed dt (24..31 zeroed); 24..55 -> bc ----
__global__ __launch_bounds__(256)
void combine1(const float* __restrict__ P, unsigned int* __restrict__ dtpk,
              float* __restrict__ bc)
{
    const int g = blockIdx.x * 256 + threadIdx.x;   // 4096*64
    const int m = g >> 6, c = g & 63;
    float s = 0.f;
    #pragma unroll
    for (int z = 0; z < 8; ++z)
        s += P[(size_t)z * 262144 + (size_t)m * 64 + c];
    if (c < 24) {
        dtpk[(size_t)m * 32 + c] = packf(s);
    } else {
        if (c < 32) dtpk[(size_t)m * 32 + c] = 0u;
        if (c < 56) bc[(size_t)m * 32 + (c - 24)] = s;
    }
}

// ---------------- combine out-GEMM split partials -> d_out ----------------
__global__ __launch_bounds__(256)
void combine_out(const float* __restrict__ PA, const float* __restrict__ PB,
                 float* __restrict__ out)
{
    const int g = blockIdx.x * 256 + threadIdx.x;   // 4096*96
    const size_t o = (size_t)g * 4;
    float4 a0 = *(const float4*)(PA + o);
    float4 a1 = *(const float4*)(PA + 1572864 + o);
    float4 a2 = *(const float4*)(PB + o);
    float4 a3 = *(const float4*)(PB + 1572864 + o);
    float4 r;
    r.x = a0.x + a1.x + a2.x + a3.x;
    r.y = a0.y + a1.y + a2.y + a3.y;
    r.z = a0.z + a1.z + a2.z + a3.z;
    r.w = a0.w + a1.w + a2.w + a3.w;
    *(float4*)(out + o) = r;
}

// ---------------- chunked selective scan ----------------
__global__ __launch_bounds__(256)
void scan_a2(const float* __restrict__ delta, const unsigned int* __restrict__ upk,
             const float* __restrict__ bc, const float* __restrict__ A_log,
             float* __restrict__ dsum_out, float* __restrict__ Bc)
{
    __shared__ float Bsh[CLEN][16];
    const int tid = threadIdx.x;
    const int d = blockIdx.x * 256 + tid;
    const int c = blockIdx.y, b = blockIdx.z;
    const int row0 = b * L_SEQ + c * CLEN;
    {
        int t = tid >> 4, n = tid & 15;
        Bsh[t][n] = bc[(size_t)(row0 + t) * 32 + n];
    }
    float AL2[16];
    {
        const float* ap = A_log + d * 16;
        #pragma unroll
        for (int n = 0; n < 16; ++n)
            AL2[n] = -__expf(ap[n]) * 1.44269504f;
    }
    __syncthreads();
    float h[16];
    #pragma unroll
    for (int n = 0; n < 16; ++n) h[n] = 0.f;
    float dsum = 0.f;
    const float* dp = delta + (size_t)row0 * 768 + d;
    const unsigned int* up = upk + (size_t)row0 * 768 + d;
    #pragma unroll 4
    for (int t = 0; t < CLEN; ++t) {
        float dt = dp[t * 768];
        float ut = unpackf(up[t * 768]);
        float du = dt * ut;
        dsum += dt;
        #pragma unroll
        for (int n = 0; n < 16; ++n) {
            float dA = exp2_fast(dt * AL2[n]);
            h[n] = fmaf(dA, h[n], du * Bsh[t][n]);
        }
    }
    dsum_out[(size_t)(b * 768 + d) * NCHUNK + c] = dsum;
    float* bcp = Bc + (((size_t)(b * 768 + d)) * NCHUNK + c) * 16;
    #pragma unroll
    for (int n = 0; n < 16; ++n) bcp[n] = h[n];
}

__global__ __launch_bounds__(256)
void scan_b2(const float* __restrict__ dsum, const float* __restrict__ A_log,
             float* __restrict__ BcHin)
{
    const size_t flat = (size_t)blockIdx.x * 256 + threadIdx.x;  // 0..49151
    const size_t bd = flat >> 4;
    const int n = (int)(flat & 15);
    const int d = (int)(bd % 768);
    const float AL2 = -__expf(A_log[d * 16 + n]) * 1.44269504f;
    const float* dsp = dsum + bd * NCHUNK;
    const size_t base = bd * (NCHUNK * 16) + n;
    float h = 0.f;
    for (int c = 0; c < NCHUNK; ++c) {
        size_t i = base + (size_t)c * 16;
        float a = exp2_fast(AL2 * dsp[c]);
        float bb = BcHin[i];
        BcHin[i] = h;
        h = fmaf(a, h, bb);
    }
}

__global__ __launch_bounds__(256)
void scan_c2(float* __restrict__ delta, const unsigned int* __restrict__ upk,
             const float* __restrict__ bc, const float* __restrict__ A_log,
             const float* __restrict__ Hin, const float* __restrict__ D_skip,
             const float* __restrict__ res)   // [4096][768]; y packed over delta
{
    __shared__ float Bsh[CLEN][16];
    __shared__ float Csh[CLEN][16];
    const int tid = threadIdx.x;
    const int d = blockIdx.x * 256 + tid;
    const int c = blockIdx.y, b = blockIdx.z;
    const int row0 = b * L_SEQ + c * CLEN;
    {
        int t = tid >> 4, n = tid & 15;
        const float* xp = bc + (size_t)(row0 + t) * 32;
        Bsh[t][n] = xp[n];
        Csh[t][n] = xp[16 + n];
    }
    float AL2[16];
    {
        const float* ap = A_log + d * 16;
        #pragma unroll
        for (int n = 0; n < 16; ++n)
            AL2[n] = -__expf(ap[n]) * 1.44269504f;
    }
    float h[16];
    {
        const float* hp = Hin + (((size_t)(b * 768 + d)) * NCHUNK + c) * 16;
        #pragma unroll
        for (int n = 0; n < 16; ++n) h[n] = hp[n];
    }
    const float Ds = D_skip[d];
    __syncthreads();
    float* dp = delta + (size_t)row0 * 768 + d;
    const unsigned int* up = upk + (size_t)row0 * 768 + d;
    const float* rp = res + (size_t)row0 * 768 + d;
    #pragma unroll 4
    for (int t = 0; t < CLEN; ++t) {
        float dt = dp[t * 768];
        float ut = unpackf(up[t * 768]);
        float du = dt * ut;
        float y = 0.f;
        #pragma unroll
        for (int n = 0; n < 16; ++n) {
            float dA = exp2_fast(dt * AL2[n]);
            h[n] = fmaf(dA, h[n], du * Bsh[t][n]);
            y = fmaf(h[n], Csh[t][n], y);
        }
        float rr = rp[t * 768];
        float gy = fmaf(ut, Ds, y) * silu_f(rr);
        dp[t * 768] = __builtin_bit_cast(float, packf(gy));
    }
}

extern "C" void kernel_launch(void* const* d_in, const int* in_sizes, int n_in,
                              void* d_out, int out_size, void* d_ws, size_t ws_size,
                              hipStream_t stream)
{
    const float* ev     = (const float*)d_in[0];
    const float* rgb    = (const float*)d_in[1];
    const float* W_ev   = (const float*)d_in[2];
    const float* b_ev   = (const float*)d_in[3];
    const float* W_rgb  = (const float*)d_in[4];
    const float* b_rgb  = (const float*)d_in[5];
    const float* ln_g   = (const float*)d_in[6];
    const float* ln_b   = (const float*)d_in[7];
    const float* W_proj = (const float*)d_in[8];
    const float* b_proj = (const float*)d_in[9];
    const float* W_in   = (const float*)d_in[10];
    const float* conv_w = (const float*)d_in[11];
    const float* conv_b = (const float*)d_in[12];
    const float* W_x    = (const float*)d_in[13];
    const float* W_dt   = (const float*)d_in[14];
    const float* b_dt   = (const float*)d_in[15];
    const float* A_log  = (const float*)d_in[16];
    const float* D_skip = (const float*)d_in[17];
    const float* W_out  = (const float*)d_in[18];
    float* out = (float*)d_out;

    // workspace (float units), total 16,877,440 fl = 67.5 MB
    float* ws = (float*)d_ws;
    const size_t O0 = 0;            // res; apk (prep->embed)
    const size_t O1 = 3145728;      // ep0/ep1 -> u_pre -> dtpk -> out partials z0,z1
    const size_t O2 = 6422528;      // xf planes + wpi -> upk
    const size_t O3 = 9568256;      // wti,wpd early -> delta
    const size_t O4 = 12713984;     // GEMM1 partials -> dsum+BcHin -> out partials z2,z3
    const size_t O5 = 16056320;     // persistent small

    float* res   = ws + O0;
    unsigned int* apk = (unsigned int*)(ws + O0);
    float* ep0   = ws + O1;
    float* ep1   = ws + O1 + 1572864;
    float* u_pre = ws + O1;
    unsigned int* dtpk = (unsigned int*)(ws + O1);
    float* outPA = ws + O1;
    unsigned int* upk = (unsigned int*)(ws + O2);
    unsigned short* xfh = (unsigned short*)(ws + O2);
    unsigned short* xfl = xfh + 1572864;
    unsigned short* wpi_hi = (unsigned short*)(ws + O2 + 1572864);
    unsigned short* wpi_lo = wpi_hi + 589824;
    float* delta = ws + O3;
    unsigned short* wti_hi = (unsigned short*)(ws + O3);
    unsigned short* wti_lo = wti_hi + 589824;
    unsigned short* wpd_hi = (unsigned short*)(ws + O3 + 589824);
    unsigned short* wpd_lo = wpd_hi + 147456;
    float* Pz    = ws + O4;                    // 8 x 4096 x 64
    float* dsum  = ws + O4;
    float* BcHin = ws + O4 + 196608;
    float* outPB = ws + O4;
    // O5 zone (fixed layout, all disjoint):
    // wct [O5, +98304) | biascat | bias_pi | wto [O5+100224, +294912) |
    // bc [O5+395136, +131072) | wx56t [O5+526208, +98304) | wdtT [O5+624512, +24576)
    unsigned short* wct_hi = (unsigned short*)(ws + O5);
    unsigned short* wct_lo = wct_hi + 98304;
    float* biascat = ws + O5 + 98304;
    float* bias_pi = ws + O5 + 98688;
    unsigned short* wto_hi = (unsigned short*)(ws + O5 + 100224);
    unsigned short* wto_lo = wto_hi + 294912;     // FIXED: was +589824 (overlapped bc/wx56t)
    float* bc    = ws + O5 + 395136;
    unsigned short* wx56t_hi = (unsigned short*)(ws + O5 + 526208);
    unsigned short* wx56t_lo = wx56t_hi + 98304;
    unsigned short* wdtT_hi = (unsigned short*)(ws + O5 + 624512);
    unsigned short* wdtT_lo = wdtT_hi + 24576;

    dim3 blk(256);

    // prep: weight conversions + embed pack
    prep_all<<<3336, blk, 0, stream>>>(
        W_in, W_out, W_x, W_dt, W_proj, b_proj, W_ev, W_rgb, b_ev, b_rgb, ev, rgb,
        wti_hi, wti_lo, wto_hi, wto_lo, wct_hi, wct_lo, wpd_hi, wpd_lo,
        wx56t_hi, wx56t_lo, wdtT_hi, wdtT_lo, biascat, bias_pi, apk);

    // embed: [ev|rgb] @ blockdiag, split-K x2 -> f32 partials
    gemm_bf3<true, 3, 2><<<dim3(3, 32, 2), blk, 0, stream>>>(
        nullptr, nullptr, apk, 256, wct_hi, wct_lo, nullptr,
        ep0, ep1, nullptr, nullptr, 128, 256, 384);
    // W_pi^T = W_in^T @ W_proj^T  (MFMA, hi/lo out) [1536][384]
    gemm_bf3<false, 1, 1><<<dim3(3, 12), blk, 0, stream>>>(
        wti_hi, wti_lo, nullptr, 384, wpd_hi, wpd_lo, nullptr,
        nullptr, nullptr, wpi_hi, wpi_lo, 384, 384, 384);
    // LN: combine embed partials + bias, write xf planes
    ln2<<<1024, blk, 0, stream>>>(ep0, ep1, biascat, ln_g, ln_b, xfh, xfl);
    // big GEMM: LN_out @ W_pi + bias_pi -> u_pre | res
    gemm_bf3<false, 4, 1><<<dim3(12, 32), blk, 0, stream>>>(
        xfh, xfl, nullptr, 384, wpi_hi, wpi_lo, bias_pi,
        u_pre, res, nullptr, nullptr, 384, 384, 1536);
    // conv + silu -> packed u
    conv_pack<<<dim3(3, 64, 4), blk, 0, stream>>>(u_pre, conv_w, conv_b, upk);
    // GEMM1: x_dbl = u @ Wx[:, :56] (N=64 padded), split-K x8 -> partials
    gemm_bf3<true, 3, 8><<<dim3(1, 32, 8), blk, 0, stream>>>(
        nullptr, nullptr, upk, 768, wx56t_hi, wx56t_lo, nullptr,
        Pz, Pz + 1048576, nullptr, nullptr, 96, 768, 64);
    // combine1: dt (packed) + bc
    combine1<<<1024, blk, 0, stream>>>(Pz, dtpk, bc);
    // GEMM2: delta = softplus(dt @ W_dt^T + b_dt), K=32 (padded), one step
    gemm_bf3<true, 6, 1><<<dim3(6, 32), blk, 0, stream>>>(
        nullptr, nullptr, dtpk, 32, wdtT_hi, wdtT_lo, b_dt,
        delta, nullptr, nullptr, nullptr, 32, 32, 768);
    // chunked scan
    scan_a2<<<dim3(3, NCHUNK, 4), blk, 0, stream>>>(delta, upk, bc, A_log, dsum, BcHin);
    scan_b2<<<192, blk, 0, stream>>>(dsum, A_log, BcHin);
    scan_c2<<<dim3(3, NCHUNK, 4), blk, 0, stream>>>(delta, upk, bc, A_log, BcHin, D_skip, res);
    // out GEMM split-K x4 -> partials -> combine
    gemm_bf3<true, 3, 4><<<dim3(3, 32, 4), blk, 0, stream>>>(
        nullptr, nullptr, (const unsigned int*)delta, 768, wto_hi, wto_lo, nullptr,
        outPA, outPB, nullptr, nullptr, 192, 768, 384);
    combine_out<<<1536, blk, 0, stream>>>(outPA, outPB, out);
}

// Round 11
// 237.341 us; speedup vs baseline: 1.2578x; 1.0324x over previous
//
#include <hip/hip_runtime.h>
#include <cstddef>
#include <cstdint>

#define L_SEQ 1024
#define NCHUNK 64
#define CLEN 16

typedef __bf16 bf16x8 __attribute__((ext_vector_type(8)));
typedef float f32x4 __attribute__((ext_vector_type(4)));

__device__ __forceinline__ float silu_f(float x) {
    return x / (1.f + __expf(-x));
}
__device__ __forceinline__ float exp2_fast(float x) { return exp2f(x); }

__device__ __forceinline__ unsigned short f2bf(float x) {
    union { float f; unsigned int u; } v; v.f = x;
    unsigned int r = (v.u + 0x7fffu + ((v.u >> 16) & 1u)) >> 16;
    return (unsigned short)r;
}
__device__ __forceinline__ float bf2f(unsigned short h) {
    union { float f; unsigned int u; } v; v.u = ((unsigned int)h) << 16;
    return v.f;
}
__device__ __forceinline__ unsigned int packf(float x) {
    unsigned short h = f2bf(x);
    unsigned short l = f2bf(x - bf2f(h));
    return ((unsigned int)h << 16) | (unsigned int)l;
}
__device__ __forceinline__ float unpackf(unsigned int pk) {
    return bf2f((unsigned short)(pk >> 16)) + bf2f((unsigned short)(pk & 0xffffu));
}

// ---------------- bf16x3 MFMA GEMM: 64x64 tile, BK=32, 4 waves (32x32 each) --------
// Small tile -> 20KB LDS, 16 VGPR acc -> 8 blocks/CU capacity; grids 512-1536 blocks
// give 3-6 blocks/CU (TLP hides latency; the 128-tile variant was stuck at 1 block/CU).
// Per K-step: store_lds -> barrier -> issue next loads -> MFMA -> barrier.
// Split-K via blockIdx.z. XCD swizzle when per-z grid %8==0.
// EPI 1: bf16 hi/lo planes (ldc=Nw). EPI 3: raw f32 partial to Cf/Cf2 (half the z's
// each), partial stride = M*Nw. EPI 4: +bias; cols<768 -> Cf, else Cf2.
// EPI 6: softplus(o + bias[nn]) -> Cf with ldc=Nw.
template<bool APK, int EPI, int SPLITS>
__global__ __launch_bounds__(256)
void gemm_bf3(const unsigned short* __restrict__ Ahi,
              const unsigned short* __restrict__ Alo,
              const unsigned int* __restrict__ Apk, int lda,
              const unsigned short* __restrict__ Bthi,
              const unsigned short* __restrict__ Btlo,
              const float* __restrict__ bias,
              float* __restrict__ Cf, float* __restrict__ Cf2,
              unsigned short* __restrict__ Chi, unsigned short* __restrict__ Clo,
              int Ks, int Ktot, int Nw)
{
    __shared__ unsigned short As[2][64][40];   // [plane][row][k]
    __shared__ unsigned short Bs[2][64][40];
    const int tid = threadIdx.x;
    const int lane = tid & 63;
    const int wave = tid >> 6;
    const int wm = wave >> 1, wn = wave & 1;

    const int gx = gridDim.x;
    const int nwg = gx * gridDim.y;
    const int lin = blockIdx.y * gx + blockIdx.x;
    const int swz = ((nwg & 7) == 0) ? ((lin & 7) * (nwg >> 3) + (lin >> 3)) : lin;
    const int m0 = (swz / gx) * 64, n0 = (swz % gx) * 64;
    const int z = (SPLITS > 1) ? blockIdx.z : 0;
    const int kbeg = z * Ks;

    const int srow = tid >> 2, sko = (tid & 3) * 8;

    f32x4 acc[2][2];
    #pragma unroll
    for (int i = 0; i < 2; ++i)
        #pragma unroll
        for (int j = 0; j < 2; ++j) {
            f32x4 zz = {0.f, 0.f, 0.f, 0.f};
            acc[i][j] = zz;
        }

    const size_t aoff = (size_t)(m0 + srow) * lda + sko;
    const size_t boff = (size_t)(n0 + srow) * Ktot + sko;

    uint4 ra[2], rb[2];

    auto load_regs = [&](int k0) {
        if constexpr (APK) {
            const unsigned int* ap = Apk + aoff + k0;
            ra[0] = *(const uint4*)(ap);
            ra[1] = *(const uint4*)(ap + 4);
        } else {
            ra[0] = *(const uint4*)(Ahi + aoff + k0);
            ra[1] = *(const uint4*)(Alo + aoff + k0);
        }
        rb[0] = *(const uint4*)(Bthi + boff + k0);
        rb[1] = *(const uint4*)(Btlo + boff + k0);
    };

    auto store_lds = [&]() {
        uint4 h, l;
        if constexpr (APK) {
            uint4 p0 = ra[0], p1 = ra[1];
            h.x = (p0.x >> 16) | (p0.y & 0xffff0000u);
            h.y = (p0.z >> 16) | (p0.w & 0xffff0000u);
            h.z = (p1.x >> 16) | (p1.y & 0xffff0000u);
            h.w = (p1.z >> 16) | (p1.w & 0xffff0000u);
            l.x = (p0.x & 0xffffu) | (p0.y << 16);
            l.y = (p0.z & 0xffffu) | (p0.w << 16);
            l.z = (p1.x & 0xffffu) | (p1.y << 16);
            l.w = (p1.z & 0xffffu) | (p1.w << 16);
        } else {
            h = ra[0]; l = ra[1];
        }
        *(uint4*)&As[0][srow][sko] = h;
        *(uint4*)&As[1][srow][sko] = l;
        *(uint4*)&Bs[0][srow][sko] = rb[0];
        *(uint4*)&Bs[1][srow][sko] = rb[1];
    };

    const int fr = lane & 15, kq = lane >> 4;
    const int kend = kbeg + Ks;

    load_regs(kbeg);
    for (int k0 = kbeg; k0 < kend; k0 += 32) {
        store_lds();
        __syncthreads();
        if (k0 + 32 < kend) load_regs(k0 + 32);
        {
            bf16x8 aH[2], aL[2];
            #pragma unroll
            for (int i = 0; i < 2; ++i) {
                aH[i] = *(const bf16x8*)&As[0][wm * 32 + i * 16 + fr][kq * 8];
                aL[i] = *(const bf16x8*)&As[1][wm * 32 + i * 16 + fr][kq * 8];
            }
            #pragma unroll
            for (int j = 0; j < 2; ++j) {
                bf16x8 bH = *(const bf16x8*)&Bs[0][wn * 32 + j * 16 + fr][kq * 8];
                bf16x8 bL = *(const bf16x8*)&Bs[1][wn * 32 + j * 16 + fr][kq * 8];
                #pragma unroll
                for (int i = 0; i < 2; ++i)
                    acc[i][j] = __builtin_amdgcn_mfma_f32_16x16x32_bf16(aH[i], bH, acc[i][j], 0, 0, 0);
                #pragma unroll
                for (int i = 0; i < 2; ++i)
                    acc[i][j] = __builtin_amdgcn_mfma_f32_16x16x32_bf16(aL[i], bH, acc[i][j], 0, 0, 0);
                #pragma unroll
                for (int i = 0; i < 2; ++i)
                    acc[i][j] = __builtin_amdgcn_mfma_f32_16x16x32_bf16(aH[i], bL, acc[i][j], 0, 0, 0);
            }
        }
        __syncthreads();
    }

    // epilogue
    float* myP = nullptr;
    if constexpr (EPI == 3) {
        float* base = (2 * z >= SPLITS) ? Cf2 : Cf;
        int sub = z - ((2 * z >= SPLITS) ? SPLITS / 2 : 0);
        myP = base + (size_t)sub * (size_t)(gridDim.y * 64) * Nw;
    }
    const int col = lane & 15, rq = lane >> 4;
    #pragma unroll
    for (int j = 0; j < 2; ++j) {
        int nn = n0 + wn * 32 + j * 16 + col;
        float bv = 0.f;
        if constexpr (EPI == 1 || EPI == 4 || EPI == 6) { if (bias) bv = bias[nn]; }
        #pragma unroll
        for (int i = 0; i < 2; ++i) {
            int mb = m0 + wm * 32 + i * 16 + rq * 4;
            #pragma unroll
            for (int r = 0; r < 4; ++r) {
                float o = acc[i][j][r] + bv;
                if constexpr (EPI == 1) {
                    unsigned short h = f2bf(o);
                    Chi[(size_t)(mb + r) * Nw + nn] = h;
                    Clo[(size_t)(mb + r) * Nw + nn] = f2bf(o - bf2f(h));
                } else if constexpr (EPI == 3) {
                    if (nn < Nw) myP[(size_t)(mb + r) * Nw + nn] = o;
                } else if constexpr (EPI == 4) {
                    if (nn < 768) Cf[(size_t)(mb + r) * 768 + nn] = o;
                    else          Cf2[(size_t)(mb + r) * 768 + (nn - 768)] = o;
                } else if constexpr (EPI == 6) {
                    float sp = fmaxf(o, 0.f) + log1pf(expf(-fabsf(o)));
                    Cf[(size_t)(mb + r) * Nw + nn] = sp;
                }
            }
        }
    }
}

// ---------------- fused one-shot prep ----------------
__device__ __forceinline__ void wcvt_body(const float* __restrict__ W,
                                          unsigned short* __restrict__ Thi,
                                          unsigned short* __restrict__ Tlo,
                                          int K, int N, int nx, int local, int tid,
                                          float* t /* [32][33] */)
{
    const int n0 = (local % nx) * 32, k0 = (local / nx) * 32;
    const int r = tid >> 3, c4 = (tid & 7) * 4;
    float4 v = *(const float4*)(W + (size_t)(k0 + r) * N + n0 + c4);
    t[r * 33 + c4 + 0] = v.x; t[r * 33 + c4 + 1] = v.y;
    t[r * 33 + c4 + 2] = v.z; t[r * 33 + c4 + 3] = v.w;
    __syncthreads();
    unsigned short hs[4], ls[4];
    #pragma unroll
    for (int j = 0; j < 4; ++j) {
        float x = t[(c4 + j) * 33 + r];
        hs[j] = f2bf(x);
        ls[j] = f2bf(x - bf2f(hs[j]));
    }
    size_t o = (size_t)(n0 + r) * K + k0 + c4;
    uint2 hv, lv;
    hv.x = (unsigned)hs[0] | ((unsigned)hs[1] << 16);
    hv.y = (unsigned)hs[2] | ((unsigned)hs[3] << 16);
    lv.x = (unsigned)ls[0] | ((unsigned)ls[1] << 16);
    lv.y = (unsigned)ls[2] | ((unsigned)ls[3] << 16);
    *(uint2*)(Thi + o) = hv;
    *(uint2*)(Tlo + o) = lv;
}

// Regions: [0,576) wti; [576,864) wto; [864,1250) wct+biascat; [1250,2274) embed pack;
// [2274,2850) wpd; [2850,2856) bias_pi; [2856,3240) wx56t; [3240,3336) wdtT.
__global__ __launch_bounds__(256)
void prep_all(const float* __restrict__ W_in, const float* __restrict__ W_out,
              const float* __restrict__ W_x, const float* __restrict__ W_dt,
              const float* __restrict__ W_proj, const float* __restrict__ b_proj,
              const float* __restrict__ W_ev, const float* __restrict__ W_rgb,
              const float* __restrict__ b_ev, const float* __restrict__ b_rgb,
              const float* __restrict__ ev, const float* __restrict__ rgb,
              unsigned short* __restrict__ wti_hi, unsigned short* __restrict__ wti_lo,
              unsigned short* __restrict__ wto_hi, unsigned short* __restrict__ wto_lo,
              unsigned short* __restrict__ wct_hi, unsigned short* __restrict__ wct_lo,
              unsigned short* __restrict__ wpd_hi, unsigned short* __restrict__ wpd_lo,
              unsigned short* __restrict__ wx56t_hi, unsigned short* __restrict__ wx56t_lo,
              unsigned short* __restrict__ wdtT_hi, unsigned short* __restrict__ wdtT_lo,
              float* __restrict__ biascat, float* __restrict__ bias_pi,
              unsigned int* __restrict__ apk)
{
    __shared__ float t[32 * 33];
    const int blk = blockIdx.x;
    const int tid = threadIdx.x;
    if (blk < 576) {
        wcvt_body(W_in, wti_hi, wti_lo, 384, 1536, 48, blk, tid, t);
    } else if (blk < 864) {
        wcvt_body(W_out, wto_hi, wto_lo, 768, 384, 12, blk - 576, tid, t);
    } else if (blk < 1250) {
        const int flat = (blk - 864) * 256 + tid;
        if (flat < 384 * 256) {
            const int n = flat >> 8, k = flat & 255;
            float val = 0.f;
            if (n < 192) { if (k < 128) val = W_ev[(size_t)k * 192 + n]; }
            else         { if (k >= 128) val = W_rgb[(size_t)(k - 128) * 192 + (n - 192)]; }
            unsigned short h = f2bf(val);
            wct_hi[flat] = h;
            wct_lo[flat] = f2bf(val - bf2f(h));
        } else if (flat < 384 * 256 + 384) {
            const int i = flat - 384 * 256;
            biascat[i] = (i < 192) ? b_ev[i] : b_rgb[i - 192];
        }
    } else if (blk < 2274) {
        const int idx = (blk - 1250) * 1024 + tid * 4;  // 4096*256 elems
        const int m = idx >> 8, kk = idx & 255;
        #pragma unroll
        for (int q = 0; q < 4; ++q) {
            int k = kk + q;
            float val = (k < 128) ? ev[(size_t)m * 128 + k] : rgb[(size_t)m * 128 + k - 128];
            apk[(size_t)m * 256 + k] = packf(val);
        }
    } else if (blk < 2850) {
        // wpd = W_proj row-major hi/lo split (Bt for the W_pi GEMM)
        const int flat = (blk - 2274) * 256 + tid;      // 384*384
        float val = W_proj[flat];
        unsigned short h = f2bf(val);
        wpd_hi[flat] = h;
        wpd_lo[flat] = f2bf(val - bf2f(h));
    } else if (blk < 2856) {
        // bias_pi[j] = sum_i b_proj[i] * W_in[i][j]
        const int j = (blk - 2850) * 256 + tid;         // 1536
        float acc = 0.f;
        for (int i = 0; i < 384; ++i)
            acc = fmaf(b_proj[i], W_in[(size_t)i * 1536 + j], acc);
        bias_pi[j] = acc;
    } else if (blk < 3240) {
        // wx56t[128][768]: rows 0..55 = W_x[:, :56]^T, rows 56..127 = 0
        const int flat = (blk - 2856) * 256 + tid;      // 128*768
        const int r = flat / 768, k = flat % 768;
        float val = (r < 56) ? W_x[(size_t)k * 56 + r] : 0.f;
        unsigned short h = f2bf(val);
        wx56t_hi[(size_t)r * 768 + k] = h;
        wx56t_lo[(size_t)r * 768 + k] = f2bf(val - bf2f(h));
    } else {
        // wdtT[768][32]: cols 0..23 = W_dt^T, cols 24..31 = 0
        const int flat = (blk - 3240) * 256 + tid;      // 768*32
        const int j = flat >> 5, kk = flat & 31;
        float val = (kk < 24) ? W_dt[(size_t)kk * 768 + j] : 0.f;
        unsigned short h = f2bf(val);
        wdtT_hi[(size_t)j * 32 + kk] = h;
        wdtT_lo[(size_t)j * 32 + kk] = f2bf(val - bf2f(h));
    }
}

// ---------------- LN over 384: sums embed split-partials + bias, writes hi/lo planes ----------------
__global__ __launch_bounds__(256)
void ln2(const float* __restrict__ ep0, const float* __restrict__ ep1,
         const float* __restrict__ biascat,
         const float* __restrict__ g, const float* __restrict__ b,
         unsigned short* __restrict__ hi, unsigned short* __restrict__ lo)
{
    const int lane = threadIdx.x & 63;
    const int row = blockIdx.x * 4 + (threadIdx.x >> 6);
    const float* p0 = ep0 + (size_t)row * 384;
    const float* p1 = ep1 + (size_t)row * 384;
    unsigned short* ph = hi + (size_t)row * 384;
    unsigned short* pl = lo + (size_t)row * 384;
    float v[6];
    #pragma unroll
    for (int i = 0; i < 6; ++i) {
        int c = i * 64 + lane;
        v[i] = p0[c] + p1[c] + biascat[c];
    }
    float s = v[0] + v[1] + v[2] + v[3] + v[4] + v[5];
    #pragma unroll
    for (int m = 32; m >= 1; m >>= 1) s += __shfl_xor(s, m);
    const float mu = s * (1.f / 384.f);
    float q = 0.f;
    #pragma unroll
    for (int i = 0; i < 6; ++i) { float dv = v[i] - mu; q = fmaf(dv, dv, q); }
    #pragma unroll
    for (int m = 32; m >= 1; m >>= 1) q += __shfl_xor(q, m);
    const float inv = 1.f / sqrtf(q * (1.f / 384.f) + 1e-5f);
    #pragma unroll
    for (int i = 0; i < 6; ++i) {
        int c = i * 64 + lane;
        float o = (v[i] - mu) * inv * g[c] + b[c];
        unsigned short h = f2bf(o);
        ph[c] = h;
        pl[c] = f2bf(o - bf2f(h));
    }
}

// ------- depthwise causal conv(4) + SiLU -> packed u; u_pre is [4096][768] -------
__global__ __launch_bounds__(256)
void conv_pack(const float* __restrict__ u_pre, const float* __restrict__ conv_w,
               const float* __restrict__ conv_b, unsigned int* __restrict__ upk)
{
    const int d = blockIdx.x * 256 + threadIdx.x;
    const int t0 = blockIdx.z * L_SEQ + blockIdx.y * 16;
    const float w0 = conv_w[d * 4 + 0], w1 = conv_w[d * 4 + 1];
    const float w2 = conv_w[d * 4 + 2], w3 = conv_w[d * 4 + 3];
    const float cb = conv_b[d];
    const float* xp = u_pre + (size_t)t0 * 768 + d;
    float x1, x2, x3;
    if (blockIdx.y == 0) { x1 = x2 = x3 = 0.f; }
    else {
        x1 = xp[-1 * 768];
        x2 = xp[-2 * 768];
        x3 = xp[-3 * 768];
    }
    unsigned int* op = upk + (size_t)t0 * 768 + d;
    #pragma unroll 4
    for (int i = 0; i < 16; ++i) {
        float cur = xp[i * 768];
        float a = cb;
        a = fmaf(x3, w0, a);
        a = fmaf(x2, w1, a);
        a = fmaf(x1, w2, a);
        a = fmaf(cur, w3, a);
        op[i * 768] = packf(silu_f(a));
        x3 = x2; x2 = x1; x1 = cur;
    }
}

// ---- combine GEMM1 split partials: cols 0..23 -> packed dt (24..31 zeroed); 24..55 -> bc ----
__global__ __launch_bounds__(256)
void combine1(const float* __restrict__ P, unsigned int* __restrict__ dtpk,
              float* __restrict__ bc)
{
    const int g = blockIdx.x * 256 + threadIdx.x;   // 4096*64
    const int m = g >> 6, c = g & 63;
    float s = 0.f;
    #pragma unroll
    for (int z = 0; z < 8; ++z)
        s += P[(size_t)z * 262144 + (size_t)m * 64 + c];
    if (c < 24) {
        dtpk[(size_t)m * 32 + c] = packf(s);
    } else {
        if (c < 32) dtpk[(size_t)m * 32 + c] = 0u;
        if (c < 56) bc[(size_t)m * 32 + (c - 24)] = s;
    }
}

// ---------------- combine out-GEMM split partials -> d_out ----------------
__global__ __launch_bounds__(256)
void combine_out(const float* __restrict__ PA, const float* __restrict__ PB,
                 float* __restrict__ out)
{
    const int g = blockIdx.x * 256 + threadIdx.x;   // 4096*96
    const size_t o = (size_t)g * 4;
    float4 a0 = *(const float4*)(PA + o);
    float4 a1 = *(const float4*)(PA + 1572864 + o);
    float4 a2 = *(const float4*)(PB + o);
    float4 a3 = *(const float4*)(PB + 1572864 + o);
    float4 r;
    r.x = a0.x + a1.x + a2.x + a3.x;
    r.y = a0.y + a1.y + a2.y + a3.y;
    r.z = a0.z + a1.z + a2.z + a3.z;
    r.w = a0.w + a1.w + a2.w + a3.w;
    *(float4*)(out + o) = r;
}

// ---------------- chunked selective scan ----------------
__global__ __launch_bounds__(256)
void scan_a2(const float* __restrict__ delta, const unsigned int* __restrict__ upk,
             const float* __restrict__ bc, const float* __restrict__ A_log,
             float* __restrict__ dsum_out, float* __restrict__ Bc)
{
    __shared__ float Bsh[CLEN][16];
    const int tid = threadIdx.x;
    const int d = blockIdx.x * 256 + tid;
    const int c = blockIdx.y, b = blockIdx.z;
    const int row0 = b * L_SEQ + c * CLEN;
    {
        int t = tid >> 4, n = tid & 15;
        Bsh[t][n] = bc[(size_t)(row0 + t) * 32 + n];
    }
    float AL2[16];
    {
        const float* ap = A_log + d * 16;
        #pragma unroll
        for (int n = 0; n < 16; ++n)
            AL2[n] = -__expf(ap[n]) * 1.44269504f;
    }
    __syncthreads();
    float h[16];
    #pragma unroll
    for (int n = 0; n < 16; ++n) h[n] = 0.f;
    float dsum = 0.f;
    const float* dp = delta + (size_t)row0 * 768 + d;
    const unsigned int* up = upk + (size_t)row0 * 768 + d;
    #pragma unroll 4
    for (int t = 0; t < CLEN; ++t) {
        float dt = dp[t * 768];
        float ut = unpackf(up[t * 768]);
        float du = dt * ut;
        dsum += dt;
        #pragma unroll
        for (int n = 0; n < 16; ++n) {
            float dA = exp2_fast(dt * AL2[n]);
            h[n] = fmaf(dA, h[n], du * Bsh[t][n]);
        }
    }
    dsum_out[(size_t)(b * 768 + d) * NCHUNK + c] = dsum;
    float* bcp = Bc + (((size_t)(b * 768 + d)) * NCHUNK + c) * 16;
    #pragma unroll
    for (int n = 0; n < 16; ++n) bcp[n] = h[n];
}

__global__ __launch_bounds__(256)
void scan_b2(const float* __restrict__ dsum, const float* __restrict__ A_log,
             float* __restrict__ BcHin)
{
    const size_t flat = (size_t)blockIdx.x * 256 + threadIdx.x;  // 0..49151
    const size_t bd = flat >> 4;
    const int n = (int)(flat & 15);
    const int d = (int)(bd % 768);
    const float AL2 = -__expf(A_log[d * 16 + n]) * 1.44269504f;
    const float* dsp = dsum + bd * NCHUNK;
    const size_t base = bd * (NCHUNK * 16) + n;
    float h = 0.f;
    for (int c = 0; c < NCHUNK; ++c) {
        size_t i = base + (size_t)c * 16;
        float a = exp2_fast(AL2 * dsp[c]);
        float bb = BcHin[i];
        BcHin[i] = h;
        h = fmaf(a, h, bb);
    }
}

__global__ __launch_bounds__(256)
void scan_c2(float* __restrict__ delta, const unsigned int* __restrict__ upk,
             const float* __restrict__ bc, const float* __restrict__ A_log,
             const float* __restrict__ Hin, const float* __restrict__ D_skip,
             const float* __restrict__ res)   // [4096][768]; y packed over delta
{
    __shared__ float Bsh[CLEN][16];
    __shared__ float Csh[CLEN][16];
    const int tid = threadIdx.x;
    const int d = blockIdx.x * 256 + tid;
    const int c = blockIdx.y, b = blockIdx.z;
    const int row0 = b * L_SEQ + c * CLEN;
    {
        int t = tid >> 4, n = tid & 15;
        const float* xp = bc + (size_t)(row0 + t) * 32;
        Bsh[t][n] = xp[n];
        Csh[t][n] = xp[16 + n];
    }
    float AL2[16];
    {
        const float* ap = A_log + d * 16;
        #pragma unroll
        for (int n = 0; n < 16; ++n)
            AL2[n] = -__expf(ap[n]) * 1.44269504f;
    }
    float h[16];
    {
        const float* hp = Hin + (((size_t)(b * 768 + d)) * NCHUNK + c) * 16;
        #pragma unroll
        for (int n = 0; n < 16; ++n) h[n] = hp[n];
    }
    const float Ds = D_skip[d];
    __syncthreads();
    float* dp = delta + (size_t)row0 * 768 + d;
    const unsigned int* up = upk + (size_t)row0 * 768 + d;
    const float* rp = res + (size_t)row0 * 768 + d;
    #pragma unroll 4
    for (int t = 0; t < CLEN; ++t) {
        float dt = dp[t * 768];
        float ut = unpackf(up[t * 768]);
        float du = dt * ut;
        float y = 0.f;
        #pragma unroll
        for (int n = 0; n < 16; ++n) {
            float dA = exp2_fast(dt * AL2[n]);
            h[n] = fmaf(dA, h[n], du * Bsh[t][n]);
            y = fmaf(h[n], Csh[t][n], y);
        }
        float rr = rp[t * 768];
        float gy = fmaf(ut, Ds, y) * silu_f(rr);
        dp[t * 768] = __builtin_bit_cast(float, packf(gy));
    }
}

extern "C" void kernel_launch(void* const* d_in, const int* in_sizes, int n_in,
                              void* d_out, int out_size, void* d_ws, size_t ws_size,
                              hipStream_t stream)
{
    const float* ev     = (const float*)d_in[0];
    const float* rgb    = (const float*)d_in[1];
    const float* W_ev   = (const float*)d_in[2];
    const float* b_ev   = (const float*)d_in[3];
    const float* W_rgb  = (const float*)d_in[4];
    const float* b_rgb  = (const float*)d_in[5];
    const float* ln_g   = (const float*)d_in[6];
    const float* ln_b   = (const float*)d_in[7];
    const float* W_proj = (const float*)d_in[8];
    const float* b_proj = (const float*)d_in[9];
    const float* W_in   = (const float*)d_in[10];
    const float* conv_w = (const float*)d_in[11];
    const float* conv_b = (const float*)d_in[12];
    const float* W_x    = (const float*)d_in[13];
    const float* W_dt   = (const float*)d_in[14];
    const float* b_dt   = (const float*)d_in[15];
    const float* A_log  = (const float*)d_in[16];
    const float* D_skip = (const float*)d_in[17];
    const float* W_out  = (const float*)d_in[18];
    float* out = (float*)d_out;

    // workspace (float units), total 16,877,440 fl = 67.5 MB
    float* ws = (float*)d_ws;
    const size_t O0 = 0;            // res; apk (prep->embed)
    const size_t O1 = 3145728;      // ep0/ep1 -> u_pre -> dtpk -> out partials z0,z1
    const size_t O2 = 6422528;      // xf planes + wpi -> upk
    const size_t O3 = 9568256;      // wti,wpd early -> delta
    const size_t O4 = 12713984;     // GEMM1 partials -> dsum+BcHin -> out partials z2,z3
    const size_t O5 = 16056320;     // persistent small

    float* res   = ws + O0;
    unsigned int* apk = (unsigned int*)(ws + O0);
    float* ep0   = ws + O1;
    float* ep1   = ws + O1 + 1572864;
    float* u_pre = ws + O1;
    unsigned int* dtpk = (unsigned int*)(ws + O1);
    float* outPA = ws + O1;
    unsigned int* upk = (unsigned int*)(ws + O2);
    unsigned short* xfh = (unsigned short*)(ws + O2);
    unsigned short* xfl = xfh + 1572864;
    unsigned short* wpi_hi = (unsigned short*)(ws + O2 + 1572864);
    unsigned short* wpi_lo = wpi_hi + 589824;
    float* delta = ws + O3;
    unsigned short* wti_hi = (unsigned short*)(ws + O3);
    unsigned short* wti_lo = wti_hi + 589824;
    unsigned short* wpd_hi = (unsigned short*)(ws + O3 + 589824);
    unsigned short* wpd_lo = wpd_hi + 147456;
    float* Pz    = ws + O4;                    // 8 x 4096 x 64
    float* dsum  = ws + O4;
    float* BcHin = ws + O4 + 196608;
    float* outPB = ws + O4;
    // O5 zone (all disjoint):
    // wct [O5, +98304 sh x2) | biascat | bias_pi | wto [O5+100224, +294912 sh x2) |
    // bc [O5+395136, +131072 fl) | wx56t [O5+526208, +98304 sh x2) | wdtT [O5+624512, +24576 sh x2)
    unsigned short* wct_hi = (unsigned short*)(ws + O5);
    unsigned short* wct_lo = wct_hi + 98304;
    float* biascat = ws + O5 + 98304;
    float* bias_pi = ws + O5 + 98688;
    unsigned short* wto_hi = (unsigned short*)(ws + O5 + 100224);
    unsigned short* wto_lo = wto_hi + 294912;
    float* bc    = ws + O5 + 395136;
    unsigned short* wx56t_hi = (unsigned short*)(ws + O5 + 526208);
    unsigned short* wx56t_lo = wx56t_hi + 98304;
    unsigned short* wdtT_hi = (unsigned short*)(ws + O5 + 624512);
    unsigned short* wdtT_lo = wdtT_hi + 24576;

    dim3 blk(256);

    // prep: weight conversions + embed pack
    prep_all<<<3336, blk, 0, stream>>>(
        W_in, W_out, W_x, W_dt, W_proj, b_proj, W_ev, W_rgb, b_ev, b_rgb, ev, rgb,
        wti_hi, wti_lo, wto_hi, wto_lo, wct_hi, wct_lo, wpd_hi, wpd_lo,
        wx56t_hi, wx56t_lo, wdtT_hi, wdtT_lo, biascat, bias_pi, apk);

    // embed: [ev|rgb] @ blockdiag, split-K x2 -> f32 partials (768 blocks)
    gemm_bf3<true, 3, 2><<<dim3(6, 64, 2), blk, 0, stream>>>(
        nullptr, nullptr, apk, 256, wct_hi, wct_lo, nullptr,
        ep0, ep1, nullptr, nullptr, 128, 256, 384);
    // W_pi^T = W_in^T @ W_proj^T  (MFMA, hi/lo out) [1536][384] (144 blocks)
    gemm_bf3<false, 1, 1><<<dim3(6, 24), blk, 0, stream>>>(
        wti_hi, wti_lo, nullptr, 384, wpd_hi, wpd_lo, nullptr,
        nullptr, nullptr, wpi_hi, wpi_lo, 384, 384, 384);
    // LN: combine embed partials + bias, write xf planes
    ln2<<<1024, blk, 0, stream>>>(ep0, ep1, biascat, ln_g, ln_b, xfh, xfl);
    // big GEMM: LN_out @ W_pi + bias_pi -> u_pre | res (1536 blocks)
    gemm_bf3<false, 4, 1><<<dim3(24, 64), blk, 0, stream>>>(
        xfh, xfl, nullptr, 384, wpi_hi, wpi_lo, bias_pi,
        u_pre, res, nullptr, nullptr, 384, 384, 1536);
    // conv + silu -> packed u
    conv_pack<<<dim3(3, 64, 4), blk, 0, stream>>>(u_pre, conv_w, conv_b, upk);
    // GEMM1: x_dbl = u @ Wx[:, :56] (N=64 padded), split-K x8 -> partials (512 blocks)
    gemm_bf3<true, 3, 8><<<dim3(1, 64, 8), blk, 0, stream>>>(
        nullptr, nullptr, upk, 768, wx56t_hi, wx56t_lo, nullptr,
        Pz, Pz + 1048576, nullptr, nullptr, 96, 768, 64);
    // combine1: dt (packed) + bc
    combine1<<<1024, blk, 0, stream>>>(Pz, dtpk, bc);
    // GEMM2: delta = softplus(dt @ W_dt^T + b_dt), K=32 (padded), one step (768 blocks)
    gemm_bf3<true, 6, 1><<<dim3(12, 64), blk, 0, stream>>>(
        nullptr, nullptr, dtpk, 32, wdtT_hi, wdtT_lo, b_dt,
        delta, nullptr, nullptr, nullptr, 32, 32, 768);
    // chunked scan
    scan_a2<<<dim3(3, NCHUNK, 4), blk, 0, stream>>>(delta, upk, bc, A_log, dsum, BcHin);
    scan_b2<<<192, blk, 0, stream>>>(dsum, A_log, BcHin);
    scan_c2<<<dim3(3, NCHUNK, 4), blk, 0, stream>>>(delta, upk, bc, A_log, BcHin, D_skip, res);
    // out GEMM split-K x4 -> partials -> combine (1536 blocks)
    gemm_bf3<true, 3, 4><<<dim3(6, 64, 4), blk, 0, stream>>>(
        nullptr, nullptr, (const unsigned int*)delta, 768, wto_hi, wto_lo, nullptr,
        outPA, outPB, nullptr, nullptr, 192, 768, 384);
    combine_out<<<1536, blk, 0, stream>>>(outPA, outPB, out);
}